// Round 1
// baseline (13779.729 us; speedup 1.0000x reference)
//
#include <hip/hip_runtime.h>
#include <float.h>

#define V 50000
#define E 100
#define H 512
#define T 200
#define B 256
#define NC 5

// ---------------- activations (fast, ~2e-7 abs err) ----------------
__device__ __forceinline__ float fsig(float x)  { return 1.f / (1.f + __expf(-x)); }
__device__ __forceinline__ float ftanh(float x) { return 1.f - 2.f / (__expf(2.f * x) + 1.f); }

// ---------------- init: zero states, hmax=-FLT_MAX, last[b] ----------------
__global__ void k_init(float* __restrict__ ws, const int* __restrict__ X,
                       int* __restrict__ last) {
    int i = blockIdx.x * 256 + threadIdx.x;
    if (i < 6 * B * H)       ws[i] = 0.f;        // h0a,h0b,c0,h1a,h1b,c1
    else if (i < 7 * B * H)  ws[i] = -FLT_MAX;   // hmax
    if (i < B) {
        int l = -1;
        const int* xr = X + i * T;
        for (int t = 0; t < T; ++t)
            if (xr[t] != V) l = t;
        last[i] = l;
    }
}

// ---------------- GEMM tile helpers ----------------
// hS: [k=32][b=34pad]  (A fragment, b-tile of 32 rows)
// wS: [k=32][c=64]     (W fragment, c = jl*4 + gate)

__device__ __forceinline__ void stageA_dense(float hS[32][34], const float* __restrict__ A,
                                             int bbase, int kt, int tid) {
    int bl = tid >> 3;            // 0..31
    int e4 = (tid & 7) * 4;       // 0..28
    const float4 v = *(const float4*)(A + (size_t)(bbase + bl) * H + kt + e4);
    hS[e4 + 0][bl] = v.x; hS[e4 + 1][bl] = v.y;
    hS[e4 + 2][bl] = v.z; hS[e4 + 3][bl] = v.w;
}

__device__ __forceinline__ void stageA_emb(float hS[32][34], const float* __restrict__ emb,
                                           const int* __restrict__ X, int t,
                                           int bbase, int kt, int tid) {
    int bl = tid >> 3;
    int e4 = (tid & 7) * 4;
    int e  = kt + e4;             // global k (padded to 128)
    float4 v = make_float4(0.f, 0.f, 0.f, 0.f);
    if (e < E) {                  // e multiple of 4; e=96 reads 96..99, in range
        int row = X[(bbase + bl) * T + t];
        v = *(const float4*)(emb + (size_t)row * E + e);
    }
    hS[e4 + 0][bl] = v.x; hS[e4 + 1][bl] = v.y;
    hS[e4 + 2][bl] = v.z; hS[e4 + 3][bl] = v.w;
}

__device__ __forceinline__ void stageW(float wS[32][64], const float* __restrict__ Wmat,
                                       int ldw, int Klim, int jbase, int kt, int tid) {
    int cc = tid >> 2;            // 0..63  (c = jc*4 + g)
    int k8 = (tid & 3) * 8;       // 0,8,16,24
    int g  = cc & 3;
    int jc = cc >> 2;
    const float* wrow = Wmat + (size_t)(g * H + jbase + jc) * ldw;
#pragma unroll
    for (int u = 0; u < 8; u += 4) {
        int k = kt + k8 + u;
        float4 v = make_float4(0.f, 0.f, 0.f, 0.f);
        if (k < Klim) v = *(const float4*)(wrow + k);
        wS[k8 + u + 0][cc] = v.x; wS[k8 + u + 1][cc] = v.y;
        wS[k8 + u + 2][cc] = v.z; wS[k8 + u + 3][cc] = v.w;
    }
}

__device__ __forceinline__ void mma32(const float hS[32][34], const float wS[32][64],
                                      int jl, int brow0, float (&acc)[2][4]) {
#pragma unroll
    for (int k = 0; k < 32; ++k) {
        const float2 hv = *(const float2*)&hS[k][brow0];   // brow0 even -> 8B aligned
        const float4 wv = *(const float4*)&wS[k][4 * jl];  // 16B aligned
        acc[0][0] = fmaf(hv.x, wv.x, acc[0][0]);
        acc[0][1] = fmaf(hv.x, wv.y, acc[0][1]);
        acc[0][2] = fmaf(hv.x, wv.z, acc[0][2]);
        acc[0][3] = fmaf(hv.x, wv.w, acc[0][3]);
        acc[1][0] = fmaf(hv.y, wv.x, acc[1][0]);
        acc[1][1] = fmaf(hv.y, wv.y, acc[1][1]);
        acc[1][2] = fmaf(hv.y, wv.z, acc[1][2]);
        acc[1][3] = fmaf(hv.y, wv.w, acc[1][3]);
    }
}

// ---------------- one LSTM step for one layer ----------------
// Computes gates = xin @ Wih^T + hprev @ Whh^T + bias, then updates c, hnew,
// and (layer 1) the running max-pool. xin==nullptr means layer 0 (embed gather).
__global__ __launch_bounds__(256) void k_step(
    int t,
    const int* __restrict__ X, const float* __restrict__ emb,
    const float* __restrict__ xin,
    const float* __restrict__ Wih, const float* __restrict__ Whh,
    const float* __restrict__ bias,
    const float* __restrict__ hprev, float* __restrict__ hnew,
    float* __restrict__ c,
    float* __restrict__ hmax, const int* __restrict__ lastp)
{
    __shared__ float hS[32][34];
    __shared__ float wS[32][64];

    const int tid   = threadIdx.x;
    const int bi    = blockIdx.x & 7;    // 8 b-tiles of 32
    const int ji    = blockIdx.x >> 3;   // 32 j-tiles of 16
    const int bbase = bi * 32;
    const int jbase = ji * 16;
    const int jl    = tid & 15;
    const int bg    = tid >> 4;          // 0..15
    const int brow0 = 2 * bg;

    float acc[2][4] = {{0.f, 0.f, 0.f, 0.f}, {0.f, 0.f, 0.f, 0.f}};

    if (xin) {
        // input part: K = 512 dense
        for (int kt = 0; kt < H; kt += 32) {
            stageA_dense(hS, xin, bbase, kt, tid);
            stageW(wS, Wih, H, H, jbase, kt, tid);
            __syncthreads();
            mma32(hS, wS, jl, brow0, acc);
            __syncthreads();
        }
    } else {
        // input part: embedding gather, K = 100 padded to 128
        for (int kt = 0; kt < 128; kt += 32) {
            stageA_emb(hS, emb, X, t, bbase, kt, tid);
            stageW(wS, Wih, E, E, jbase, kt, tid);
            __syncthreads();
            mma32(hS, wS, jl, brow0, acc);
            __syncthreads();
        }
    }
    // recurrent part: K = 512
    for (int kt = 0; kt < H; kt += 32) {
        stageA_dense(hS, hprev, bbase, kt, tid);
        stageW(wS, Whh, H, H, jbase, kt, tid);
        __syncthreads();
        mma32(hS, wS, jl, brow0, acc);
        __syncthreads();
    }

    const int j = jbase + jl;
    const float b_i = bias[0 * H + j];
    const float b_f = bias[1 * H + j];
    const float b_g = bias[2 * H + j];
    const float b_o = bias[3 * H + j];

#pragma unroll
    for (int r = 0; r < 2; ++r) {
        const int b = bbase + brow0 + r;
        float ig = fsig (acc[r][0] + b_i);
        float fg = fsig (acc[r][1] + b_f);
        float gg = ftanh(acc[r][2] + b_g);
        float og = fsig (acc[r][3] + b_o);
        float cp = c[b * H + j];
        float cn = fg * cp + ig * gg;
        float hn = og * ftanh(cn);
        c[b * H + j]    = cn;
        hnew[b * H + j] = hn;
        if (hmax != nullptr) {
            if (t <= lastp[b]) {
                float m = hmax[b * H + j];
                hmax[b * H + j] = fmaxf(m, hn);
            }
        }
    }
}

// ---------------- final: logits = hmax @ Wout^T + bout ----------------
__global__ __launch_bounds__(256) void k_out(const float* __restrict__ hmax,
                                             const float* __restrict__ Wout,
                                             const float* __restrict__ bout,
                                             float* __restrict__ out) {
    __shared__ float red[NC][256];
    const int b = blockIdx.x, tid = threadIdx.x;
    float a[NC] = {0.f, 0.f, 0.f, 0.f, 0.f};
    for (int h = tid; h < H; h += 256) {
        float hv = hmax[b * H + h];
#pragma unroll
        for (int cls = 0; cls < NC; ++cls)
            a[cls] = fmaf(hv, Wout[cls * H + h], a[cls]);
    }
#pragma unroll
    for (int cls = 0; cls < NC; ++cls) red[cls][tid] = a[cls];
    __syncthreads();
    for (int s = 128; s > 0; s >>= 1) {
        if (tid < s) {
#pragma unroll
            for (int cls = 0; cls < NC; ++cls)
                red[cls][tid] += red[cls][tid + s];
        }
        __syncthreads();
    }
    if (tid < NC) out[b * NC + tid] = red[tid][0] + bout[tid];
}

// ---------------- launch ----------------
extern "C" void kernel_launch(void* const* d_in, const int* in_sizes, int n_in,
                              void* d_out, int out_size, void* d_ws, size_t ws_size,
                              hipStream_t stream) {
    const int*   X    = (const int*)  d_in[0];
    const float* emb  = (const float*)d_in[1];
    const float* Wih0 = (const float*)d_in[2];
    const float* Whh0 = (const float*)d_in[3];
    const float* b0   = (const float*)d_in[4];
    const float* Wih1 = (const float*)d_in[5];
    const float* Whh1 = (const float*)d_in[6];
    const float* b1   = (const float*)d_in[7];
    const float* Wout = (const float*)d_in[8];
    const float* bout = (const float*)d_in[9];
    float* out = (float*)d_out;
    float* ws  = (float*)d_ws;

    const int BH = B * H;
    float* h0a  = ws + 0 * BH;
    float* h0b  = ws + 1 * BH;
    float* c0   = ws + 2 * BH;
    float* h1a  = ws + 3 * BH;
    float* h1b  = ws + 4 * BH;
    float* c1   = ws + 5 * BH;
    float* hmax = ws + 6 * BH;
    int*   last = (int*)(ws + 7 * BH);

    k_init<<<(7 * BH + 255) / 256, 256, 0, stream>>>(ws, X, last);

    for (int t = 0; t < T; ++t) {
        float* h0p = (t & 1) ? h0b : h0a;
        float* h0n = (t & 1) ? h0a : h0b;
        float* h1p = (t & 1) ? h1b : h1a;
        float* h1n = (t & 1) ? h1a : h1b;
        // layer 0 (embedding input)
        k_step<<<256, 256, 0, stream>>>(t, X, emb, nullptr, Wih0, Whh0, b0,
                                        h0p, h0n, c0, nullptr, nullptr);
        // layer 1 (input = h0n), fused max-pool update
        k_step<<<256, 256, 0, stream>>>(t, X, emb, h0n, Wih1, Whh1, b1,
                                        h1p, h1n, c1, hmax, last);
    }

    k_out<<<B, 256, 0, stream>>>(hmax, Wout, bout, out);
}